// Round 4
// baseline (3033.209 us; speedup 1.0000x reference)
//
#include <hip/hip_runtime.h>

#define PROP_ALPHA 0.1f
#define PROP_KSTEPS 10

// ---------------- CSR build ----------------

__global__ void hist_kernel(const int* __restrict__ dst, int* __restrict__ degI, int E) {
    int e = blockIdx.x * blockDim.x + threadIdx.x;
    if (e < E) atomicAdd(&degI[dst[e]], 1);
}

__global__ void dinv_kernel(const int* __restrict__ degI, float* __restrict__ dinv, int N) {
    int i = blockIdx.x * blockDim.x + threadIdx.x;
    if (i < N) {
        float d = (float)(degI[i] + 1);   // + self loop
        dinv[i] = rsqrtf(d);
    }
}

// ---- 3-kernel device-wide exclusive scan (N <= 256*256) ----

__global__ __launch_bounds__(256) void scan1_kernel(const int* __restrict__ degI,
                                                    int* __restrict__ rowptr,
                                                    int* __restrict__ blockSums, int N) {
    __shared__ int s[256];
    int t = threadIdx.x;
    int idx = blockIdx.x * 256 + t;
    s[t] = (idx < N) ? degI[idx] : 0;
    __syncthreads();
    for (int off = 1; off < 256; off <<= 1) {
        int x = (t >= off) ? s[t - off] : 0;
        __syncthreads();
        s[t] += x;
        __syncthreads();
    }
    if (idx < N) rowptr[idx + 1] = s[t];           // block-local inclusive
    if (t == 255) blockSums[blockIdx.x] = s[255];
    if (blockIdx.x == 0 && t == 0) rowptr[0] = 0;
}

__global__ __launch_bounds__(256) void scan2_kernel(int* __restrict__ blockSums, int nB) {
    __shared__ int s[256];
    int t = threadIdx.x;
    s[t] = (t < nB) ? blockSums[t] : 0;
    __syncthreads();
    for (int off = 1; off < 256; off <<= 1) {
        int x = (t >= off) ? s[t - off] : 0;
        __syncthreads();
        s[t] += x;
        __syncthreads();
    }
    if (t < nB) blockSums[t] = (t == 0) ? 0 : s[t - 1];   // exclusive
}

__global__ void scan3_kernel(int* __restrict__ rowptr, const int* __restrict__ blockSums,
                             int N) {
    int idx = blockIdx.x * 256 + threadIdx.x;
    if (idx < N) rowptr[idx + 1] += blockSums[blockIdx.x];
}

// edata[p] = { src, bitcast(norm) }
__global__ void scatter_kernel(const int* __restrict__ src, const int* __restrict__ dst,
                               const int* __restrict__ rowptr, int* __restrict__ rowctr,
                               const float* __restrict__ dinv,
                               int2* __restrict__ edata, int E) {
    int e = blockIdx.x * blockDim.x + threadIdx.x;
    if (e < E) {
        int d = dst[e], s = src[e];
        int p = rowptr[d] + atomicAdd(&rowctr[d], 1);
        int2 ed;
        ed.x = s;
        ed.y = __float_as_int(dinv[s] * dinv[d]);
        edata[p] = ed;
    }
}

// ---------------- fused MLP: h2 = relu(zx@W3 + v*b3^T)@W4 + b4 ----------------
// W columns hoisted to registers straight from global (L2-hot).
// zsT/tsT transposed in LDS so one broadcast ds_read_b128 feeds a 4-row quartet.

__global__ __launch_bounds__(256) void fusedmlp_kernel(const float* __restrict__ zx,
                                                       const float* __restrict__ v,
                                                       const float* __restrict__ W3,
                                                       const float* __restrict__ b3,
                                                       const float* __restrict__ W4,
                                                       const float* __restrict__ b4,
                                                       float* __restrict__ h2, int N) {
    __shared__ float zsT[64 * 36];    // [k][row], padded stride 36
    __shared__ float tsT[128 * 36];   // [k][row]
    __shared__ float vs[32];
    int t = threadIdx.x;
    int r0 = blockIdx.x * 32;
    int rows = min(32, N - r0);

    // stage zx rows (transposed) + v
    for (int idx = t; idx < rows * 64; idx += 256) {
        int r = idx >> 6, c = idx & 63;
        zsT[c * 36 + r] = zx[(size_t)r0 * 64 + idx];
    }
    if (t < 32) vs[t] = (t < rows) ? v[r0 + t] : 0.0f;
    __syncthreads();

    // ---- layer 1: tsT = relu(zsT^T @ W3 + vs*b3), 128 cols x 32 rows ----
    {
        int col = t & 127;          // 0..127
        int rhalf = t >> 7;         // 0..1 -> rows rhalf*16 .. +15
        float wcol[64];
        #pragma unroll
        for (int k = 0; k < 64; ++k) wcol[k] = W3[k * 128 + col];
        float bc = b3[col];
        #pragma unroll
        for (int rq = 0; rq < 4; ++rq) {
            int rb = rhalf * 16 + rq * 4;
            float a0 = vs[rb + 0] * bc;
            float a1 = vs[rb + 1] * bc;
            float a2 = vs[rb + 2] * bc;
            float a3 = vs[rb + 3] * bc;
            #pragma unroll
            for (int k = 0; k < 64; ++k) {
                float4 zq = *reinterpret_cast<const float4*>(&zsT[k * 36 + rb]);
                a0 += zq.x * wcol[k];
                a1 += zq.y * wcol[k];
                a2 += zq.z * wcol[k];
                a3 += zq.w * wcol[k];
            }
            float4 o;
            o.x = fmaxf(a0, 0.0f); o.y = fmaxf(a1, 0.0f);
            o.z = fmaxf(a2, 0.0f); o.w = fmaxf(a3, 0.0f);
            *reinterpret_cast<float4*>(&tsT[col * 36 + rb]) = o;
        }
    }
    __syncthreads();

    // ---- layer 2: h2 = tsT^T @ W4 + b4, 64 cols x 32 rows ----
    {
        int col = t & 63;           // 0..63
        int rg = t >> 6;            // 0..3 -> rows rg*8 .. +7
        int rb0 = rg * 8;
        float bc = b4[col];
        float a[8];
        #pragma unroll
        for (int j = 0; j < 8; ++j) a[j] = bc;
        #pragma unroll
        for (int kh = 0; kh < 2; ++kh) {
            float wcol[64];
            #pragma unroll
            for (int k = 0; k < 64; ++k) wcol[k] = W4[(size_t)(kh * 64 + k) * 64 + col];
            #pragma unroll
            for (int k = 0; k < 64; ++k) {
                int kk = kh * 64 + k;
                float4 q0 = *reinterpret_cast<const float4*>(&tsT[kk * 36 + rb0]);
                float4 q1 = *reinterpret_cast<const float4*>(&tsT[kk * 36 + rb0 + 4]);
                a[0] += q0.x * wcol[k]; a[1] += q0.y * wcol[k];
                a[2] += q0.z * wcol[k]; a[3] += q0.w * wcol[k];
                a[4] += q1.x * wcol[k]; a[5] += q1.y * wcol[k];
                a[6] += q1.z * wcol[k]; a[7] += q1.w * wcol[k];
            }
        }
        #pragma unroll
        for (int j = 0; j < 8; ++j) {
            int r = rb0 + j;
            if (r < rows) h2[(size_t)(r0 + r) * 64 + col] = a[j];
        }
    }
}

// ---------------- propagation ----------------

// ones-vector propagation, wave per node, shuffle reduce
__global__ __launch_bounds__(256) void propvec_kernel(const float* __restrict__ vin,
                                                      const int* __restrict__ rowptr,
                                                      const int2* __restrict__ edata,
                                                      const float* __restrict__ dinv,
                                                      float* __restrict__ vout,
                                                      int N, int firstOnes) {
    int wave = threadIdx.x >> 6, lane = threadIdx.x & 63;
    int i = blockIdx.x * 4 + wave;
    if (i >= N) return;
    i = __builtin_amdgcn_readfirstlane(i);
    int beg = rowptr[i], end = rowptr[i + 1];
    float di = dinv[i];
    float acc = 0.0f;
    for (int e = beg + lane; e < end; e += 64) {
        int2 ed = edata[e];
        float w = __int_as_float(ed.y);
        acc += w * (firstOnes ? 1.0f : vin[ed.x]);
    }
    #pragma unroll
    for (int off = 32; off >= 1; off >>= 1) acc += __shfl_xor(acc, off);
    if (lane == 0) {
        float self = firstOnes ? 1.0f : vin[i];
        vout[i] = (1.0f - PROP_ALPHA) * (acc + di * di * self) + PROP_ALPHA;
    }
}

// channel-chunked propagation: chunk = 16 channels, [chunk][N][16] layout (3.2 MB/chunk
// fits per-XCD L2). Wave = 1 node: 16 lanes per channel x 4 edges in parallel.
// zpitch/opitch select chunked (N*16) vs strided [N][64] (16) views.
__global__ __launch_bounds__(256) void prop16_kernel(const float* __restrict__ zin,
                                                     long zpitch, int zstride,
                                                     const float* __restrict__ h,
                                                     const int* __restrict__ rowptr,
                                                     const int2* __restrict__ edata,
                                                     const float* __restrict__ dinv,
                                                     float* __restrict__ zout,
                                                     long opitch, int ostride,
                                                     int N, int blocksPerChunk) {
    int chunk = blockIdx.x / blocksPerChunk;
    int nb = blockIdx.x % blocksPerChunk;
    int wave = threadIdx.x >> 6, lane = threadIdx.x & 63;
    int eg = lane >> 4, c = lane & 15;
    int i = nb * 4 + wave;
    if (i >= N) return;
    i = __builtin_amdgcn_readfirstlane(i);
    int beg = rowptr[i], end = rowptr[i + 1];
    float di = dinv[i];
    const float* zp = zin + (size_t)chunk * zpitch;
    float* op = zout + (size_t)chunk * opitch;

    float acc0 = 0.0f, acc1 = 0.0f;
    if (eg == 0) acc0 = di * di * zp[(size_t)i * zstride + c];
    int e = beg + eg;
    for (; e + 4 < end; e += 8) {
        int2 ed0 = edata[e];
        int2 ed1 = edata[e + 4];
        acc0 += __int_as_float(ed0.y) * zp[(size_t)ed0.x * zstride + c];
        acc1 += __int_as_float(ed1.y) * zp[(size_t)ed1.x * zstride + c];
    }
    if (e < end) {
        int2 ed = edata[e];
        acc0 += __int_as_float(ed.y) * zp[(size_t)ed.x * zstride + c];
    }
    float acc = acc0 + acc1;
    acc += __shfl_xor(acc, 16);
    acc += __shfl_xor(acc, 32);
    if (lane < 16) {
        float hv = h[(size_t)i * 64 + chunk * 16 + c];
        op[(size_t)i * ostride + c] = (1.0f - PROP_ALPHA) * acc + PROP_ALPHA * hv;
    }
}

// ---------------- launch ----------------

extern "C" void kernel_launch(void* const* d_in, const int* in_sizes, int n_in,
                              void* d_out, int out_size, void* d_ws, size_t ws_size,
                              hipStream_t stream) {
    const float* x  = (const float*)d_in[0];
    const int*   ei = (const int*)d_in[1];
    const float* W3 = (const float*)d_in[2];
    const float* b3 = (const float*)d_in[3];
    const float* W4 = (const float*)d_in[4];
    const float* b4 = (const float*)d_in[5];
    float* out = (float*)d_out;

    int N = in_sizes[0] / 64;   // IN_CH = 64
    int E = in_sizes[1] / 2;
    const int* srcA = ei;
    const int* dstA = ei + E;

    char* ws = (char*)d_ws;
    size_t off = 0;
    auto alloc = [&](size_t bytes) -> void* {
        void* p = ws + off;
        off = (off + bytes + 255) & ~(size_t)255;
        return p;
    };

    int nScanB = (N + 255) / 256;

    int*   degI   = (int*)alloc((size_t)N * 4);
    int*   rowptr = (int*)alloc(((size_t)N + 1) * 4);
    int*   rowctr = (int*)alloc((size_t)N * 4);
    int*   bsums  = (int*)alloc((size_t)nScanB * 4);
    float* dinv   = (float*)alloc((size_t)N * 4);
    int2*  edata  = (int2*)alloc((size_t)E * 8);
    float* vA     = (float*)alloc((size_t)N * 4);
    float* vB     = (float*)alloc((size_t)N * 4);
    float* zA     = (float*)alloc((size_t)N * 64 * 4);
    float* zB     = (float*)alloc((size_t)N * 64 * 4);
    float* hbuf   = (float*)alloc((size_t)N * 64 * 4);

    hipMemsetAsync(degI, 0, (size_t)N * 4, stream);
    hipMemsetAsync(rowctr, 0, (size_t)N * 4, stream);

    // --- CSR build ---
    hist_kernel<<<(E + 255) / 256, 256, 0, stream>>>(dstA, degI, E);
    dinv_kernel<<<(N + 255) / 256, 256, 0, stream>>>(degI, dinv, N);
    scan1_kernel<<<nScanB, 256, 0, stream>>>(degI, rowptr, bsums, N);
    scan2_kernel<<<1, 256, 0, stream>>>(bsums, nScanB);
    scan3_kernel<<<nScanB, 256, 0, stream>>>(rowptr, bsums, N);
    scatter_kernel<<<(E + 255) / 256, 256, 0, stream>>>(srcA, dstA, rowptr, rowctr,
                                                        dinv, edata, E);

    int bpc = (N + 3) / 4;            // blocks per chunk (wave = 1 node, 4 waves/block)
    int propGrid = 4 * bpc;           // 4 channel-chunks
    long chunkedPitch = (long)N * 16;

    // --- v = M * ones ---
    for (int s = 0; s < PROP_KSTEPS; ++s) {
        const float* in = (s == 0) ? vA /*unused*/ : ((s & 1) ? vA : vB);
        float*       o  = (s & 1) ? vB : vA;
        propvec_kernel<<<bpc, 256, 0, stream>>>(in, rowptr, edata, dinv, o, N,
                                                s == 0 ? 1 : 0);
    }
    // final v in vB

    // --- zx = M * x : chunked prop, step0 reads x strided, step9 writes zB strided ---
    for (int s = 0; s < PROP_KSTEPS; ++s) {
        const float* in;  long zp; int zs_;
        float* o;         long op; int os_;
        if (s == 0) { in = x; zp = 16; zs_ = 64; }
        else if (s & 1) { in = zA; zp = chunkedPitch; zs_ = 16; }
        else            { in = zB; zp = chunkedPitch; zs_ = 16; }
        if (s == PROP_KSTEPS - 1) { o = zB; op = 16; os_ = 64; }
        else if (s & 1) { o = zB; op = chunkedPitch; os_ = 16; }
        else            { o = zA; op = chunkedPitch; os_ = 16; }
        prop16_kernel<<<propGrid, 256, 0, stream>>>(in, zp, zs_, x, rowptr, edata,
                                                    dinv, o, op, os_, N, bpc);
    }
    // zx (strided) in zB

    // --- h2 = relu(zx@W3 + v*b3^T)@W4 + b4 ---
    fusedmlp_kernel<<<(N + 31) / 32, 256, 0, stream>>>(zB, vB, W3, b3, W4, b4, hbuf, N);

    // --- out = M * h2 : chunked prop, step0 reads hbuf strided, step9 writes d_out ---
    for (int s = 0; s < PROP_KSTEPS; ++s) {
        const float* in;  long zp; int zs_;
        float* o;         long op; int os_;
        if (s == 0) { in = hbuf; zp = 16; zs_ = 64; }
        else if (s & 1) { in = zA; zp = chunkedPitch; zs_ = 16; }
        else            { in = zB; zp = chunkedPitch; zs_ = 16; }
        if (s == PROP_KSTEPS - 1) { o = out; op = 16; os_ = 64; }
        else if (s & 1) { o = zB; op = chunkedPitch; os_ = 16; }
        else            { o = zA; op = chunkedPitch; os_ = 16; }
        prop16_kernel<<<propGrid, 256, 0, stream>>>(in, zp, zs_, hbuf, rowptr, edata,
                                                    dinv, o, op, os_, N, bpc);
    }
}